// Round 16
// baseline (188.487 us; speedup 1.0000x reference)
//
#include <hip/hip_runtime.h>
#include <math.h>

#define NN 20000          // nodes per graph
#define NE 320000         // edges (before self loops)
#define ETOT (NE + NN)    // edges + self loops
#define NH 4              // heads
#define CH 64             // channels per head
#define HC 256            // NH*CH
#define FIN 128           // layer-1 input features
#define NEG_SLOPE 0.2f
#define CAP 64            // edges per softmax chunk (multiple of 4)
#define EST 80            // ew stride in floats (80%32=16 -> <=2-way conflicts, free)
#define SCB 79            // scan blocks: 79*256 >= NN
#define GM128 313         // (2*NN + 127) / 128

typedef unsigned short ushort_t;
typedef unsigned int uint_t;
typedef _Float16 half8 __attribute__((ext_vector_type(8)));
typedef float f32x4 __attribute__((ext_vector_type(4)));

__device__ __forceinline__ ushort_t f2h_bits(float f) {
    union { _Float16 h; ushort_t u; } c; c.h = (_Float16)f;
    return c.u;
}
__device__ __forceinline__ uint_t pack2h(float a, float b) {
    return (uint_t)f2h_bits(a) | ((uint_t)f2h_bits(b) << 16);
}

// fused f16->f32 convert + FMA: acc_lo += f16lo(word)*w ; acc_hi += f16hi(word)*w
__device__ __forceinline__ void fma_mix_pair(float& alo, float& ahi, uint_t word, float w) {
    asm("v_fma_mix_f32 %0, %1, %2, %0 op_sel:[0,0,0] op_sel_hi:[1,0,0]"
        : "+v"(alo) : "v"(word), "v"(w));
    asm("v_fma_mix_f32 %0, %1, %2, %0 op_sel:[1,0,0] op_sel_hi:[1,0,0]"
        : "+v"(ahi) : "v"(word), "v"(w));
}

// ---------------- fused hist + weight-transpose setup ----------------

#define HB ((ETOT + 255) / 256)             // hist blocks
#define SN1 (FIN * HC)                      // Wt1
#define SN2 (SN1 + HC * HC)                 // Wt2
#define SN3 (SN2 + HC * CH)                 // Wtf
#define SB ((SN3 + 255) / 256)              // setup blocks (weights only)

__global__ void k_hist_setup(const int* __restrict__ ei, int* __restrict__ counts,
                             const float* __restrict__ W1, const float* __restrict__ W2,
                             const float* __restrict__ Wf, ushort_t* __restrict__ Wt1,
                             ushort_t* __restrict__ Wt2, ushort_t* __restrict__ Wtf) {
    int blk = blockIdx.x;
    if (blk < HB) {
        int e = blk * 256 + threadIdx.x;
        if (e >= ETOT) return;
        int d = (e < NE) ? ei[NE + e] : (e - NE);
        atomicAdd(&counts[d], 1);
    } else {
        int i = (blk - HB) * 256 + threadIdx.x;
        if (i < SN1) {
            int n = i / FIN, k = i - n * FIN;
            Wt1[i] = f2h_bits(W1[(size_t)k * HC + n]);
        } else if (i < SN2) {
            int j = i - SN1;
            int n = j / HC, k = j - n * HC;
            Wt2[j] = f2h_bits(W2[(size_t)k * HC + n]);
        } else if (i < SN3) {
            int j = i - SN2;
            int n = j / HC, k = j - n * HC;
            Wtf[j] = f2h_bits(Wf[(size_t)k * CH + n]);
        }
    }
}

// ---------------- parallel scan: per-block reduce -> top scan -> apply ----------------

__global__ void k_scan_part(const int* __restrict__ counts, int* __restrict__ bsum) {
    __shared__ int red[256];
    int t = threadIdx.x;
    int i = blockIdx.x * 256 + t;
    red[t] = (i < NN) ? counts[i] : 0;
    __syncthreads();
#pragma unroll
    for (int off = 128; off > 0; off >>= 1) {
        if (t < off) red[t] += red[t + off];
        __syncthreads();
    }
    if (t == 0) bsum[blockIdx.x] = red[0];
}

__global__ void k_scan_top(const int* __restrict__ bsum, int* __restrict__ bpre) {
    __shared__ int s[128];
    int t = threadIdx.x;
    int own = (t < SCB) ? bsum[t] : 0;
    s[t] = own;
    __syncthreads();
#pragma unroll
    for (int off = 1; off < 128; off <<= 1) {
        int v = (t >= off) ? s[t - off] : 0;
        __syncthreads();
        s[t] += v;
        __syncthreads();
    }
    if (t < SCB) bpre[t] = s[t] - own;   // exclusive block prefix
}

__global__ void k_scan_apply(const int* __restrict__ counts, const int* __restrict__ bpre,
                             int* __restrict__ rowptr, int* __restrict__ cursor) {
    __shared__ int s[256];
    int t = threadIdx.x;
    int i = blockIdx.x * 256 + t;
    int c = (i < NN) ? counts[i] : 0;
    s[t] = c;
    __syncthreads();
#pragma unroll
    for (int off = 1; off < 256; off <<= 1) {
        int v = (t >= off) ? s[t - off] : 0;
        __syncthreads();
        s[t] += v;
        __syncthreads();
    }
    int ex = s[t] - c + bpre[blockIdx.x];
    if (i < NN) { rowptr[i] = ex; cursor[i] = ex; }
    if (i == NN - 1) rowptr[NN] = ex + c;
}

// ---------------- 128x128 f16 MFMA GEMM body (A = f16 or f32) + fused scores ----------------

__device__ __forceinline__ void gemm128_body(const ushort_t* __restrict__ A,
                                             const float* __restrict__ Af,
                                             const ushort_t* __restrict__ Bt,
                                             ushort_t* __restrict__ Ch,
                                             const float* __restrict__ a_src,
                                             const float* __restrict__ a_dst,
                                             float* __restrict__ ssrc,
                                             float* __restrict__ sdst,
                                             int M, int K, int NC, int row0, int col0,
                                             ushort_t* S) {
    ushort_t* As = S;             // 128*40, pad: 80B stride -> 2-way (free)
    ushort_t* Bs = S + 128 * 40;
    int tid = threadIdx.x;
    int wave = tid >> 6, lane = tid & 63;
    int wr = wave >> 1, wc = wave & 1;

    f32x4 acc[4][4];
#pragma unroll
    for (int i = 0; i < 4; ++i)
#pragma unroll
        for (int j = 0; j < 4; ++j) acc[i][j] = (f32x4){0.f, 0.f, 0.f, 0.f};

    int srow = tid >> 2;
    int sk8 = (tid & 3) * 8;
    int l15 = lane & 15, lk = (lane >> 4) * 8;

    int ra0 = min(row0 + srow, M - 1);
    int ra1 = min(row0 + 64 + srow, M - 1);

    for (int k0 = 0; k0 < K; k0 += 32) {
        uint4 a0, a1;
        if (Af) {
            const float* p0 = &Af[(size_t)ra0 * K + k0 + sk8];
            float4 f0 = *reinterpret_cast<const float4*>(p0);
            float4 f1 = *reinterpret_cast<const float4*>(p0 + 4);
            a0 = make_uint4(pack2h(f0.x, f0.y), pack2h(f0.z, f0.w),
                            pack2h(f1.x, f1.y), pack2h(f1.z, f1.w));
            const float* p1 = &Af[(size_t)ra1 * K + k0 + sk8];
            float4 g0 = *reinterpret_cast<const float4*>(p1);
            float4 g1 = *reinterpret_cast<const float4*>(p1 + 4);
            a1 = make_uint4(pack2h(g0.x, g0.y), pack2h(g0.z, g0.w),
                            pack2h(g1.x, g1.y), pack2h(g1.z, g1.w));
        } else {
            a0 = *reinterpret_cast<const uint4*>(&A[(size_t)ra0 * K + k0 + sk8]);
            a1 = *reinterpret_cast<const uint4*>(&A[(size_t)ra1 * K + k0 + sk8]);
        }
        uint4 b0 = *reinterpret_cast<const uint4*>(&Bt[(size_t)(col0 + srow) * K + k0 + sk8]);
        uint4 b1 = *reinterpret_cast<const uint4*>(&Bt[(size_t)(col0 + 64 + srow) * K + k0 + sk8]);
        __syncthreads();
        *reinterpret_cast<uint4*>(&As[srow * 40 + sk8]) = a0;
        *reinterpret_cast<uint4*>(&As[(64 + srow) * 40 + sk8]) = a1;
        *reinterpret_cast<uint4*>(&Bs[srow * 40 + sk8]) = b0;
        *reinterpret_cast<uint4*>(&Bs[(64 + srow) * 40 + sk8]) = b1;
        __syncthreads();

        half8 af[4], bf_[4];
#pragma unroll
        for (int m = 0; m < 4; ++m)
            af[m] = *reinterpret_cast<const half8*>(&As[(wr * 64 + m * 16 + l15) * 40 + lk]);
#pragma unroll
        for (int nf = 0; nf < 4; ++nf)
            bf_[nf] = *reinterpret_cast<const half8*>(&Bs[(wc * 64 + nf * 16 + l15) * 40 + lk]);
#pragma unroll
        for (int m = 0; m < 4; ++m)
#pragma unroll
            for (int nf = 0; nf < 4; ++nf)
                acc[m][nf] = __builtin_amdgcn_mfma_f32_16x16x32_f16(af[m], bf_[nf], acc[m][nf], 0, 0, 0);
    }

    // C store (f16)
#pragma unroll
    for (int m = 0; m < 4; ++m)
#pragma unroll
        for (int nf = 0; nf < 4; ++nf) {
            int colc = col0 + wc * 64 + nf * 16 + l15;
#pragma unroll
            for (int j = 0; j < 4; ++j) {
                int row = row0 + wr * 64 + m * 16 + (lane >> 4) * 4 + j;
                if (row < M) Ch[(size_t)row * NC + colc] = f2h_bits(acc[m][nf][j]);
            }
        }

    // fused scores: this wave's 64 cols = one full head
    if (ssrc) {
        int head = (col0 >> 6) + wc;
        float as4[4], ad4[4];
#pragma unroll
        for (int nf = 0; nf < 4; ++nf) {
            as4[nf] = a_src[head * 64 + nf * 16 + l15];
            ad4[nf] = a_dst[head * 64 + nf * 16 + l15];
        }
#pragma unroll
        for (int m = 0; m < 4; ++m)
#pragma unroll
            for (int j = 0; j < 4; ++j) {
                float ps = acc[m][0][j] * as4[0] + acc[m][1][j] * as4[1]
                         + acc[m][2][j] * as4[2] + acc[m][3][j] * as4[3];
                float pd = acc[m][0][j] * ad4[0] + acc[m][1][j] * ad4[1]
                         + acc[m][2][j] * ad4[2] + acc[m][3][j] * ad4[3];
#pragma unroll
                for (int off = 1; off < 16; off <<= 1) {
                    ps += __shfl_xor(ps, off);
                    pd += __shfl_xor(pd, off);
                }
                int row = row0 + wr * 64 + m * 16 + (lane >> 4) * 4 + j;
                if (l15 == 0 && row < M) {
                    ssrc[(size_t)row * NH + head] = ps;
                    sdst[(size_t)row * NH + head] = pd;
                }
            }
    }
}

__global__ __launch_bounds__(256) void k_gemm128(const ushort_t* __restrict__ A,
                                                 const ushort_t* __restrict__ Bt,
                                                 ushort_t* __restrict__ Ch,
                                                 const float* __restrict__ a_src,
                                                 const float* __restrict__ a_dst,
                                                 float* __restrict__ ssrc,
                                                 float* __restrict__ sdst,
                                                 int M, int K, int NC) {
    __shared__ ushort_t S[2 * 128 * 40];
    gemm128_body(A, nullptr, Bt, Ch, a_src, a_dst, ssrc, sdst, M, K, NC,
                 blockIdx.x * 128, blockIdx.y * 128, S);
}

// fused: CSR scatter (blocks [0,HB)) || layer-1 GEMM from f32 x (blocks [HB, HB+626))
__global__ __launch_bounds__(256) void k_scatter_gemm1(const int* __restrict__ ei,
                                                       int* __restrict__ cursor,
                                                       int* __restrict__ col,
                                                       const float* __restrict__ xf,
                                                       const ushort_t* __restrict__ Bt,
                                                       ushort_t* __restrict__ Ch,
                                                       const float* __restrict__ a_src,
                                                       const float* __restrict__ a_dst,
                                                       float* __restrict__ ssrc,
                                                       float* __restrict__ sdst,
                                                       int M) {
    __shared__ ushort_t S[2 * 128 * 40];
    if (blockIdx.x < HB) {
        int e = blockIdx.x * 256 + threadIdx.x;
        if (e >= ETOT) return;
        int s, d;
        if (e < NE) { s = ei[e]; d = ei[NE + e]; }
        else        { s = e - NE; d = s; }
        int pos = atomicAdd(&cursor[d], 1);
        col[pos] = s;
    } else {
        int g = blockIdx.x - HB;
        int row0 = (g % GM128) * 128;
        int col0 = (g / GM128) * 128;
        gemm128_body(nullptr, xf, Bt, Ch, a_src, a_dst, ssrc, sdst, M, FIN, HC,
                     row0, col0, S);
    }
}

// ---------------- 64x64 f16 MFMA GEMM (final projection, f32 out + bias) ----------------

__global__ __launch_bounds__(256) void k_gemm_mfma(const ushort_t* __restrict__ A,
                                                   const ushort_t* __restrict__ Bt,
                                                   float* __restrict__ Cf,
                                                   const float* __restrict__ bias,
                                                   int M, int K, int NC) {
    __shared__ ushort_t As[64][40];
    __shared__ ushort_t Bs[64][40];
    int tid = threadIdx.x;
    int wave = tid >> 6, lane = tid & 63;
    int wr = wave >> 1, wc = wave & 1;
    int row0 = blockIdx.x * 64, col0 = blockIdx.y * 64;

    f32x4 acc[2][2];
#pragma unroll
    for (int i = 0; i < 2; ++i)
#pragma unroll
        for (int j = 0; j < 2; ++j) acc[i][j] = (f32x4){0.f, 0.f, 0.f, 0.f};

    int sr = tid >> 2;
    int sk = (tid & 3) * 8;
    int l15 = lane & 15, lk = (lane >> 4) * 8;

    for (int k0 = 0; k0 < K; k0 += 32) {
        uint4 av = make_uint4(0, 0, 0, 0);
        int rowg = row0 + sr;
        if (rowg < M) av = *reinterpret_cast<const uint4*>(&A[(size_t)rowg * K + k0 + sk]);
        uint4 bv = *reinterpret_cast<const uint4*>(&Bt[(size_t)(col0 + sr) * K + k0 + sk]);
        __syncthreads();
        *reinterpret_cast<uint4*>(&As[sr][sk]) = av;
        *reinterpret_cast<uint4*>(&Bs[sr][sk]) = bv;
        __syncthreads();

        half8 a0 = *reinterpret_cast<const half8*>(&As[wr * 32 + l15][lk]);
        half8 a1 = *reinterpret_cast<const half8*>(&As[wr * 32 + 16 + l15][lk]);
        half8 b0 = *reinterpret_cast<const half8*>(&Bs[wc * 32 + l15][lk]);
        half8 b1 = *reinterpret_cast<const half8*>(&Bs[wc * 32 + 16 + l15][lk]);
        acc[0][0] = __builtin_amdgcn_mfma_f32_16x16x32_f16(a0, b0, acc[0][0], 0, 0, 0);
        acc[0][1] = __builtin_amdgcn_mfma_f32_16x16x32_f16(a0, b1, acc[0][1], 0, 0, 0);
        acc[1][0] = __builtin_amdgcn_mfma_f32_16x16x32_f16(a1, b0, acc[1][0], 0, 0, 0);
        acc[1][1] = __builtin_amdgcn_mfma_f32_16x16x32_f16(a1, b1, acc[1][1], 0, 0, 0);
    }

#pragma unroll
    for (int fr = 0; fr < 2; ++fr)
#pragma unroll
        for (int fc = 0; fc < 2; ++fc) {
            int colc = col0 + wc * 32 + fc * 16 + l15;
#pragma unroll
            for (int j = 0; j < 4; ++j) {
                int row = row0 + wr * 32 + fr * 16 + (lane >> 4) * 4 + j;
                if (row < M) Cf[(size_t)row * NC + colc] = acc[fr][fc][j] + bias[colc];
            }
        }
}

// ---------------- edge softmax + aggregation: one wave per (node, batch) ----------------
// Flat dispatch, 4 waves/block, batch-sequential wave mapping, no-max softmax,
// (edge,head)-parallel phase A, pad-4 chunks, 4 edges/iter with 2x16B loads in
// flight + v_fma_mix_f32. Plain __launch_bounds__ (min-waves spilled, round 9).

__global__ __launch_bounds__(256) void k_agg(const ushort_t* __restrict__ hb,  // [2*NN][HC] f16
                                             const float* __restrict__ ssrc,   // [2*NN][NH]
                                             const float* __restrict__ sdst,
                                             const int* __restrict__ rowptr,
                                             const int* __restrict__ col,
                                             const float* __restrict__ bias,
                                             ushort_t* __restrict__ outh,      // [2*NN][HC] f16
                                             int do_elu) {
    __shared__ int cols_lds[4][CAP];
    __shared__ float e_lds[4][4 * EST];
    __shared__ float den_lds[4][4];
    int wave = threadIdx.x >> 6, lane = threadIdx.x & 63;
    int gw = blockIdx.x * 4 + wave;      // global wave id in [0, 2*NN)
    int b = (gw >= NN) ? 1 : 0;
    int n = gw - b * NN;
    int* colw = cols_lds[wave];
    float* ew = e_lds[wave];
    int start = rowptr[n];
    int deg = rowptr[n + 1] - start;
    int es = lane >> 5;          // edge slot (phase C)
    int cg = lane & 31;          // channel group: ch [8cg, 8cg+8)
    int hd = cg >> 3;            // head of this lane's channels
    int ea = lane >> 2;          // edge index (phase A), 0..15
    int ha = lane & 3;           // head (phase A)

    const ushort_t* hbase = hb + (size_t)b * NN * HC;
    const float* ssrcb = ssrc + (size_t)b * NN * NH;

    float sdh = sdst[((size_t)b * NN + n) * NH + ha];

    float pdp = 0.f;
    float acc[8];
#pragma unroll
    for (int j = 0; j < 8; ++j) acc[j] = 0.f;

    const int cg8 = cg * 8;

    for (int c0 = 0; c0 < deg; c0 += CAP) {
        int cnt = min(CAP, deg - c0);
        int cnt4 = (cnt + 3) & ~3;

        // phase A: (edge,head)-parallel — 16 edges x 4 heads per step
        for (int i0 = 0; i0 < cnt4; i0 += 16) {
            int i = i0 + ea;
            if (i < cnt) {
                int s = col[start + c0 + i];
                if (ha == 0) colw[i] = s * HC;
                float e = ssrcb[(size_t)s * NH + ha] + sdh;
                e = fmaxf(e, NEG_SLOPE * e);
                float w = __expf(e);
                ew[ha * EST + i] = w;
                pdp += w;
            } else {
                if (ha == 0) colw[i] = 0;
                ew[ha * EST + i] = 0.f;
            }
        }

        // phase C: edge-parallel gather, 4 edges/iter, 2x16B loads in flight per lane,
        // fused cvt+fma via v_fma_mix_f32
        for (int i = 0; i < cnt4; i += 4) {
            int i0 = i + es, i1 = i + 2 + es;
            int o0 = colw[i0], o1 = colw[i1];
            float w0 = ew[hd * EST + i0], w1 = ew[hd * EST + i1];
            uint4 u0 = *reinterpret_cast<const uint4*>(hbase + o0 + cg8);
            uint4 u1 = *reinterpret_cast<const uint4*>(hbase + o1 + cg8);
            fma_mix_pair(acc[0], acc[1], u0.x, w0);
            fma_mix_pair(acc[2], acc[3], u0.y, w0);
            fma_mix_pair(acc[4], acc[5], u0.z, w0);
            fma_mix_pair(acc[6], acc[7], u0.w, w0);
            fma_mix_pair(acc[0], acc[1], u1.x, w1);
            fma_mix_pair(acc[2], acc[3], u1.y, w1);
            fma_mix_pair(acc[4], acc[5], u1.z, w1);
            fma_mix_pair(acc[6], acc[7], u1.w, w1);
        }
    }

    // denominator: reduce over edge groups (strides 4..32 keep head fixed)
#pragma unroll
    for (int off = 4; off < 64; off <<= 1) pdp += __shfl_xor(pdp, off);
    if (lane < 4) den_lds[wave][ha] = pdp;

    // reduce acc across edge slots
#pragma unroll
    for (int j = 0; j < 8; ++j) acc[j] += __shfl_xor(acc[j], 32);

    if (es == 0) {
        float inv = 1.0f / den_lds[wave][hd];
        float4 b0 = *reinterpret_cast<const float4*>(&bias[cg8]);
        float4 b1 = *reinterpret_cast<const float4*>(&bias[cg8 + 4]);
        float bv[8] = {b0.x, b0.y, b0.z, b0.w, b1.x, b1.y, b1.z, b1.w};
        ushort_t o[8];
#pragma unroll
        for (int j = 0; j < 8; ++j) {
            float r = acc[j] * inv + bv[j];
            if (do_elu && r < 0.f) r = expm1f(r);
            o[j] = f2h_bits(r);
        }
        *reinterpret_cast<uint4*>(&outh[((size_t)b * NN + n) * HC + cg8]) =
            *reinterpret_cast<uint4*>(&o[0]);
    }
}

// ---------------- launch ----------------

extern "C" void kernel_launch(void* const* d_in, const int* in_sizes, int n_in,
                              void* d_out, int out_size, void* d_ws, size_t ws_size,
                              hipStream_t stream) {
    const float* x      = (const float*)d_in[0];   // [2, NN, FIN]
    const int*   ei     = (const int*)d_in[1];     // [2, NE]
    const float* W1     = (const float*)d_in[2];   // [FIN, HC]
    const float* a_src1 = (const float*)d_in[3];
    const float* a_dst1 = (const float*)d_in[4];
    const float* b1     = (const float*)d_in[5];
    const float* W2     = (const float*)d_in[6];   // [HC, HC]
    const float* a_src2 = (const float*)d_in[7];
    const float* a_dst2 = (const float*)d_in[8];
    const float* b2     = (const float*)d_in[9];
    const float* Wf     = (const float*)d_in[10];  // [HC, CH]
    const float* bf     = (const float*)d_in[11];
    float* out = (float*)d_out;                    // [2, NN, CH]

    const int M2 = 2 * NN;
    float* ws = (float*)d_ws;
    float* Ssrc = ws;                              // M2*NH
    float* Sdst = Ssrc + (size_t)M2 * NH;          // M2*NH
    ushort_t* Hb16 = (ushort_t*)(Sdst + (size_t)M2 * NH);  // M2*HC f16 (gemm out)
    ushort_t* Ob16 = Hb16 + (size_t)M2 * HC;       // M2*HC f16 (agg out)
    ushort_t* Xb16 = Ob16 + (size_t)M2 * HC;       // M2*FIN f16 (unused, layout keep)
    ushort_t* Wt1  = Xb16 + (size_t)M2 * FIN;      // HC*FIN
    ushort_t* Wt2  = Wt1 + (size_t)HC * FIN;       // HC*HC
    ushort_t* Wtf  = Wt2 + (size_t)HC * HC;        // CH*HC
    int* counts = (int*)(Wtf + (size_t)CH * HC);
    int* rowptr = counts + NN;                     // NN+1
    int* cursor = rowptr + (NN + 1);
    int* colidx = cursor + NN;                     // ETOT
    int* bsum   = colidx + ETOT;                   // SCB
    int* bpre   = bsum + SCB;                      // SCB

    // ---- CSR hist (fused with weight transposes) + parallel scan ----
    hipMemsetAsync(counts, 0, (size_t)NN * sizeof(int), stream);
    k_hist_setup<<<HB + SB, 256, 0, stream>>>(ei, counts, W1, W2, Wf, Wt1, Wt2, Wtf);
    k_scan_part<<<SCB, 256, 0, stream>>>(counts, bsum);
    k_scan_top<<<1, 128, 0, stream>>>(bsum, bpre);
    k_scan_apply<<<SCB, 256, 0, stream>>>(counts, bpre, rowptr, cursor);

    const int gAgg = M2 / 4;                   // 10000 blocks x 4 waves
    // scatter || layer-1 GEMM (f32 x, scores fused into epilogue)
    k_scatter_gemm1<<<HB + GM128 * (HC / 128), 256, 0, stream>>>(
        ei, cursor, colidx, x, Wt1, Hb16, a_src1, a_dst1, Ssrc, Sdst, M2);
    k_agg<<<gAgg, 256, 0, stream>>>(Hb16, Ssrc, Sdst, rowptr, colidx, b1, Ob16, 1);
    // layer 2
    k_gemm128<<<dim3(GM128, HC / 128), 256, 0, stream>>>(Ob16, Wt2, Hb16, a_src2, a_dst2,
                                                         Ssrc, Sdst, M2, HC, HC);
    k_agg<<<gAgg, 256, 0, stream>>>(Hb16, Ssrc, Sdst, rowptr, colidx, b2, Ob16, 0);
    // final projection (64-wide): f32 out + bias
    k_gemm_mfma<<<dim3((M2 + 63) / 64, CH / 64), 256, 0, stream>>>(Ob16, Wtf, out, bf, M2, HC, CH);
}

// Round 17
// 184.568 us; speedup vs baseline: 1.0212x; 1.0212x over previous
//
#include <hip/hip_runtime.h>
#include <math.h>

#define NN 20000          // nodes per graph
#define NE 320000         // edges (before self loops)
#define ETOT (NE + NN)    // edges + self loops
#define NH 4              // heads
#define CH 64             // channels per head
#define HC 256            // NH*CH
#define FIN 128           // layer-1 input features
#define NEG_SLOPE 0.2f
#define CAP 64            // edges per softmax chunk (multiple of 8)
#define EST 80            // ew stride in floats (80%32=16 -> <=2-way conflicts, free)
#define SCB 79            // scan blocks: 79*256 >= NN
#define GM128 313         // (2*NN + 127) / 128

typedef unsigned short ushort_t;
typedef unsigned int uint_t;
typedef _Float16 half8 __attribute__((ext_vector_type(8)));
typedef float f32x4 __attribute__((ext_vector_type(4)));

__device__ __forceinline__ ushort_t f2h_bits(float f) {
    union { _Float16 h; ushort_t u; } c; c.h = (_Float16)f;
    return c.u;
}
__device__ __forceinline__ uint_t pack2h(float a, float b) {
    return (uint_t)f2h_bits(a) | ((uint_t)f2h_bits(b) << 16);
}

// fused f16->f32 convert + FMA: acc_lo += f16lo(word)*w ; acc_hi += f16hi(word)*w
__device__ __forceinline__ void fma_mix_pair(float& alo, float& ahi, uint_t word, float w) {
    asm("v_fma_mix_f32 %0, %1, %2, %0 op_sel:[0,0,0] op_sel_hi:[1,0,0]"
        : "+v"(alo) : "v"(word), "v"(w));
    asm("v_fma_mix_f32 %0, %1, %2, %0 op_sel:[1,0,0] op_sel_hi:[1,0,0]"
        : "+v"(ahi) : "v"(word), "v"(w));
}

// ---------------- fused hist + weight-transpose setup ----------------

#define HB ((ETOT + 255) / 256)             // hist blocks
#define SN1 (FIN * HC)                      // Wt1
#define SN2 (SN1 + HC * HC)                 // Wt2
#define SN3 (SN2 + HC * CH)                 // Wtf
#define SB ((SN3 + 255) / 256)              // setup blocks (weights only)

__global__ void k_hist_setup(const int* __restrict__ ei, int* __restrict__ counts,
                             const float* __restrict__ W1, const float* __restrict__ W2,
                             const float* __restrict__ Wf, ushort_t* __restrict__ Wt1,
                             ushort_t* __restrict__ Wt2, ushort_t* __restrict__ Wtf) {
    int blk = blockIdx.x;
    if (blk < HB) {
        int e = blk * 256 + threadIdx.x;
        if (e >= ETOT) return;
        int d = (e < NE) ? ei[NE + e] : (e - NE);
        atomicAdd(&counts[d], 1);
    } else {
        int i = (blk - HB) * 256 + threadIdx.x;
        if (i < SN1) {
            int n = i / FIN, k = i - n * FIN;
            Wt1[i] = f2h_bits(W1[(size_t)k * HC + n]);
        } else if (i < SN2) {
            int j = i - SN1;
            int n = j / HC, k = j - n * HC;
            Wt2[j] = f2h_bits(W2[(size_t)k * HC + n]);
        } else if (i < SN3) {
            int j = i - SN2;
            int n = j / HC, k = j - n * HC;
            Wtf[j] = f2h_bits(Wf[(size_t)k * CH + n]);
        }
    }
}

// ---------------- parallel scan: per-block reduce -> top scan -> apply ----------------

__global__ void k_scan_part(const int* __restrict__ counts, int* __restrict__ bsum) {
    __shared__ int red[256];
    int t = threadIdx.x;
    int i = blockIdx.x * 256 + t;
    red[t] = (i < NN) ? counts[i] : 0;
    __syncthreads();
#pragma unroll
    for (int off = 128; off > 0; off >>= 1) {
        if (t < off) red[t] += red[t + off];
        __syncthreads();
    }
    if (t == 0) bsum[blockIdx.x] = red[0];
}

__global__ void k_scan_top(const int* __restrict__ bsum, int* __restrict__ bpre) {
    __shared__ int s[128];
    int t = threadIdx.x;
    int own = (t < SCB) ? bsum[t] : 0;
    s[t] = own;
    __syncthreads();
#pragma unroll
    for (int off = 1; off < 128; off <<= 1) {
        int v = (t >= off) ? s[t - off] : 0;
        __syncthreads();
        s[t] += v;
        __syncthreads();
    }
    if (t < SCB) bpre[t] = s[t] - own;   // exclusive block prefix
}

__global__ void k_scan_apply(const int* __restrict__ counts, const int* __restrict__ bpre,
                             int* __restrict__ rowptr, int* __restrict__ cursor) {
    __shared__ int s[256];
    int t = threadIdx.x;
    int i = blockIdx.x * 256 + t;
    int c = (i < NN) ? counts[i] : 0;
    s[t] = c;
    __syncthreads();
#pragma unroll
    for (int off = 1; off < 256; off <<= 1) {
        int v = (t >= off) ? s[t - off] : 0;
        __syncthreads();
        s[t] += v;
        __syncthreads();
    }
    int ex = s[t] - c + bpre[blockIdx.x];
    if (i < NN) { rowptr[i] = ex; cursor[i] = ex; }
    if (i == NN - 1) rowptr[NN] = ex + c;
}

// ---------------- 128x128 f16 MFMA GEMM body (A = f16 or f32) + fused scores ----------------

__device__ __forceinline__ void gemm128_body(const ushort_t* __restrict__ A,
                                             const float* __restrict__ Af,
                                             const ushort_t* __restrict__ Bt,
                                             ushort_t* __restrict__ Ch,
                                             const float* __restrict__ a_src,
                                             const float* __restrict__ a_dst,
                                             float* __restrict__ ssrc,
                                             float* __restrict__ sdst,
                                             int M, int K, int NC, int row0, int col0,
                                             ushort_t* S) {
    ushort_t* As = S;             // 128*40, pad: 80B stride -> 2-way (free)
    ushort_t* Bs = S + 128 * 40;
    int tid = threadIdx.x;
    int wave = tid >> 6, lane = tid & 63;
    int wr = wave >> 1, wc = wave & 1;

    f32x4 acc[4][4];
#pragma unroll
    for (int i = 0; i < 4; ++i)
#pragma unroll
        for (int j = 0; j < 4; ++j) acc[i][j] = (f32x4){0.f, 0.f, 0.f, 0.f};

    int srow = tid >> 2;
    int sk8 = (tid & 3) * 8;
    int l15 = lane & 15, lk = (lane >> 4) * 8;

    int ra0 = min(row0 + srow, M - 1);
    int ra1 = min(row0 + 64 + srow, M - 1);

    for (int k0 = 0; k0 < K; k0 += 32) {
        uint4 a0, a1;
        if (Af) {
            const float* p0 = &Af[(size_t)ra0 * K + k0 + sk8];
            float4 f0 = *reinterpret_cast<const float4*>(p0);
            float4 f1 = *reinterpret_cast<const float4*>(p0 + 4);
            a0 = make_uint4(pack2h(f0.x, f0.y), pack2h(f0.z, f0.w),
                            pack2h(f1.x, f1.y), pack2h(f1.z, f1.w));
            const float* p1 = &Af[(size_t)ra1 * K + k0 + sk8];
            float4 g0 = *reinterpret_cast<const float4*>(p1);
            float4 g1 = *reinterpret_cast<const float4*>(p1 + 4);
            a1 = make_uint4(pack2h(g0.x, g0.y), pack2h(g0.z, g0.w),
                            pack2h(g1.x, g1.y), pack2h(g1.z, g1.w));
        } else {
            a0 = *reinterpret_cast<const uint4*>(&A[(size_t)ra0 * K + k0 + sk8]);
            a1 = *reinterpret_cast<const uint4*>(&A[(size_t)ra1 * K + k0 + sk8]);
        }
        uint4 b0 = *reinterpret_cast<const uint4*>(&Bt[(size_t)(col0 + srow) * K + k0 + sk8]);
        uint4 b1 = *reinterpret_cast<const uint4*>(&Bt[(size_t)(col0 + 64 + srow) * K + k0 + sk8]);
        __syncthreads();
        *reinterpret_cast<uint4*>(&As[srow * 40 + sk8]) = a0;
        *reinterpret_cast<uint4*>(&As[(64 + srow) * 40 + sk8]) = a1;
        *reinterpret_cast<uint4*>(&Bs[srow * 40 + sk8]) = b0;
        *reinterpret_cast<uint4*>(&Bs[(64 + srow) * 40 + sk8]) = b1;
        __syncthreads();

        half8 af[4], bf_[4];
#pragma unroll
        for (int m = 0; m < 4; ++m)
            af[m] = *reinterpret_cast<const half8*>(&As[(wr * 64 + m * 16 + l15) * 40 + lk]);
#pragma unroll
        for (int nf = 0; nf < 4; ++nf)
            bf_[nf] = *reinterpret_cast<const half8*>(&Bs[(wc * 64 + nf * 16 + l15) * 40 + lk]);
#pragma unroll
        for (int m = 0; m < 4; ++m)
#pragma unroll
            for (int nf = 0; nf < 4; ++nf)
                acc[m][nf] = __builtin_amdgcn_mfma_f32_16x16x32_f16(af[m], bf_[nf], acc[m][nf], 0, 0, 0);
    }

    // C store (f16)
#pragma unroll
    for (int m = 0; m < 4; ++m)
#pragma unroll
        for (int nf = 0; nf < 4; ++nf) {
            int colc = col0 + wc * 64 + nf * 16 + l15;
#pragma unroll
            for (int j = 0; j < 4; ++j) {
                int row = row0 + wr * 64 + m * 16 + (lane >> 4) * 4 + j;
                if (row < M) Ch[(size_t)row * NC + colc] = f2h_bits(acc[m][nf][j]);
            }
        }

    // fused scores: this wave's 64 cols = one full head
    if (ssrc) {
        int head = (col0 >> 6) + wc;
        float as4[4], ad4[4];
#pragma unroll
        for (int nf = 0; nf < 4; ++nf) {
            as4[nf] = a_src[head * 64 + nf * 16 + l15];
            ad4[nf] = a_dst[head * 64 + nf * 16 + l15];
        }
#pragma unroll
        for (int m = 0; m < 4; ++m)
#pragma unroll
            for (int j = 0; j < 4; ++j) {
                float ps = acc[m][0][j] * as4[0] + acc[m][1][j] * as4[1]
                         + acc[m][2][j] * as4[2] + acc[m][3][j] * as4[3];
                float pd = acc[m][0][j] * ad4[0] + acc[m][1][j] * ad4[1]
                         + acc[m][2][j] * ad4[2] + acc[m][3][j] * ad4[3];
#pragma unroll
                for (int off = 1; off < 16; off <<= 1) {
                    ps += __shfl_xor(ps, off);
                    pd += __shfl_xor(pd, off);
                }
                int row = row0 + wr * 64 + m * 16 + (lane >> 4) * 4 + j;
                if (l15 == 0 && row < M) {
                    ssrc[(size_t)row * NH + head] = ps;
                    sdst[(size_t)row * NH + head] = pd;
                }
            }
    }
}

__global__ __launch_bounds__(256) void k_gemm128(const ushort_t* __restrict__ A,
                                                 const ushort_t* __restrict__ Bt,
                                                 ushort_t* __restrict__ Ch,
                                                 const float* __restrict__ a_src,
                                                 const float* __restrict__ a_dst,
                                                 float* __restrict__ ssrc,
                                                 float* __restrict__ sdst,
                                                 int M, int K, int NC) {
    __shared__ ushort_t S[2 * 128 * 40];
    gemm128_body(A, nullptr, Bt, Ch, a_src, a_dst, ssrc, sdst, M, K, NC,
                 blockIdx.x * 128, blockIdx.y * 128, S);
}

// fused: CSR scatter (blocks [0,HB)) || layer-1 GEMM from f32 x (blocks [HB, HB+626))
__global__ __launch_bounds__(256) void k_scatter_gemm1(const int* __restrict__ ei,
                                                       int* __restrict__ cursor,
                                                       int* __restrict__ col,
                                                       const float* __restrict__ xf,
                                                       const ushort_t* __restrict__ Bt,
                                                       ushort_t* __restrict__ Ch,
                                                       const float* __restrict__ a_src,
                                                       const float* __restrict__ a_dst,
                                                       float* __restrict__ ssrc,
                                                       float* __restrict__ sdst,
                                                       int M) {
    __shared__ ushort_t S[2 * 128 * 40];
    if (blockIdx.x < HB) {
        int e = blockIdx.x * 256 + threadIdx.x;
        if (e >= ETOT) return;
        int s, d;
        if (e < NE) { s = ei[e]; d = ei[NE + e]; }
        else        { s = e - NE; d = s; }
        int pos = atomicAdd(&cursor[d], 1);
        col[pos] = s;
    } else {
        int g = blockIdx.x - HB;
        int row0 = (g % GM128) * 128;
        int col0 = (g / GM128) * 128;
        gemm128_body(nullptr, xf, Bt, Ch, a_src, a_dst, ssrc, sdst, M, FIN, HC,
                     row0, col0, S);
    }
}

// ---------------- 64x64 f16 MFMA GEMM (final projection, f32 out + bias) ----------------

__global__ __launch_bounds__(256) void k_gemm_mfma(const ushort_t* __restrict__ A,
                                                   const ushort_t* __restrict__ Bt,
                                                   float* __restrict__ Cf,
                                                   const float* __restrict__ bias,
                                                   int M, int K, int NC) {
    __shared__ ushort_t As[64][40];
    __shared__ ushort_t Bs[64][40];
    int tid = threadIdx.x;
    int wave = tid >> 6, lane = tid & 63;
    int wr = wave >> 1, wc = wave & 1;
    int row0 = blockIdx.x * 64, col0 = blockIdx.y * 64;

    f32x4 acc[2][2];
#pragma unroll
    for (int i = 0; i < 2; ++i)
#pragma unroll
        for (int j = 0; j < 2; ++j) acc[i][j] = (f32x4){0.f, 0.f, 0.f, 0.f};

    int sr = tid >> 2;
    int sk = (tid & 3) * 8;
    int l15 = lane & 15, lk = (lane >> 4) * 8;

    for (int k0 = 0; k0 < K; k0 += 32) {
        uint4 av = make_uint4(0, 0, 0, 0);
        int rowg = row0 + sr;
        if (rowg < M) av = *reinterpret_cast<const uint4*>(&A[(size_t)rowg * K + k0 + sk]);
        uint4 bv = *reinterpret_cast<const uint4*>(&Bt[(size_t)(col0 + sr) * K + k0 + sk]);
        __syncthreads();
        *reinterpret_cast<uint4*>(&As[sr][sk]) = av;
        *reinterpret_cast<uint4*>(&Bs[sr][sk]) = bv;
        __syncthreads();

        half8 a0 = *reinterpret_cast<const half8*>(&As[wr * 32 + l15][lk]);
        half8 a1 = *reinterpret_cast<const half8*>(&As[wr * 32 + 16 + l15][lk]);
        half8 b0 = *reinterpret_cast<const half8*>(&Bs[wc * 32 + l15][lk]);
        half8 b1 = *reinterpret_cast<const half8*>(&Bs[wc * 32 + 16 + l15][lk]);
        acc[0][0] = __builtin_amdgcn_mfma_f32_16x16x32_f16(a0, b0, acc[0][0], 0, 0, 0);
        acc[0][1] = __builtin_amdgcn_mfma_f32_16x16x32_f16(a0, b1, acc[0][1], 0, 0, 0);
        acc[1][0] = __builtin_amdgcn_mfma_f32_16x16x32_f16(a1, b0, acc[1][0], 0, 0, 0);
        acc[1][1] = __builtin_amdgcn_mfma_f32_16x16x32_f16(a1, b1, acc[1][1], 0, 0, 0);
    }

#pragma unroll
    for (int fr = 0; fr < 2; ++fr)
#pragma unroll
        for (int fc = 0; fc < 2; ++fc) {
            int colc = col0 + wc * 32 + fc * 16 + l15;
#pragma unroll
            for (int j = 0; j < 4; ++j) {
                int row = row0 + wr * 32 + fr * 16 + (lane >> 4) * 4 + j;
                if (row < M) Cf[(size_t)row * NC + colc] = acc[fr][fc][j] + bias[colc];
            }
        }
}

// ---------------- edge softmax + aggregation: one wave per (node, batch) ----------------
// Flat dispatch, 4 waves/block, batch-sequential wave mapping, no-max softmax,
// (edge,head)-parallel phase A, pad-8 chunks, 8 edges/iter with 4x16B loads in
// flight + v_fma_mix_f32 (round-15 best-measured form: 44.1 us).
// pad-4/2-deep regressed (round 16); min-waves bound spilled (round 9).

__global__ __launch_bounds__(256) void k_agg(const ushort_t* __restrict__ hb,  // [2*NN][HC] f16
                                             const float* __restrict__ ssrc,   // [2*NN][NH]
                                             const float* __restrict__ sdst,
                                             const int* __restrict__ rowptr,
                                             const int* __restrict__ col,
                                             const float* __restrict__ bias,
                                             ushort_t* __restrict__ outh,      // [2*NN][HC] f16
                                             int do_elu) {
    __shared__ int cols_lds[4][CAP];
    __shared__ float e_lds[4][4 * EST];
    __shared__ float den_lds[4][4];
    int wave = threadIdx.x >> 6, lane = threadIdx.x & 63;
    int gw = blockIdx.x * 4 + wave;      // global wave id in [0, 2*NN)
    int b = (gw >= NN) ? 1 : 0;
    int n = gw - b * NN;
    int* colw = cols_lds[wave];
    float* ew = e_lds[wave];
    int start = rowptr[n];
    int deg = rowptr[n + 1] - start;
    int es = lane >> 5;          // edge slot (phase C)
    int cg = lane & 31;          // channel group: ch [8cg, 8cg+8)
    int hd = cg >> 3;            // head of this lane's channels
    int ea = lane >> 2;          // edge index (phase A), 0..15
    int ha = lane & 3;           // head (phase A)

    const ushort_t* hbase = hb + (size_t)b * NN * HC;
    const float* ssrcb = ssrc + (size_t)b * NN * NH;

    float sdh = sdst[((size_t)b * NN + n) * NH + ha];

    float pdp = 0.f;
    float acc[8];
#pragma unroll
    for (int j = 0; j < 8; ++j) acc[j] = 0.f;

    const int cg8 = cg * 8;

    for (int c0 = 0; c0 < deg; c0 += CAP) {
        int cnt = min(CAP, deg - c0);
        int cnt8 = (cnt + 7) & ~7;

        // phase A: (edge,head)-parallel — 16 edges x 4 heads per step
        for (int i0 = 0; i0 < cnt8; i0 += 16) {
            int i = i0 + ea;
            if (i < cnt) {
                int s = col[start + c0 + i];
                if (ha == 0) colw[i] = s * HC;
                float e = ssrcb[(size_t)s * NH + ha] + sdh;
                e = fmaxf(e, NEG_SLOPE * e);
                float w = __expf(e);
                ew[ha * EST + i] = w;
                pdp += w;
            } else {
                if (ha == 0) colw[i] = 0;
                ew[ha * EST + i] = 0.f;
            }
        }

        // phase C: edge-parallel gather, 8 edges/iter, 4x16B loads in flight per lane,
        // fused cvt+fma via v_fma_mix_f32
        for (int i = 0; i < cnt8; i += 8) {
            int i0 = i + es, i1 = i + 2 + es, i2 = i + 4 + es, i3 = i + 6 + es;
            int o0 = colw[i0], o1 = colw[i1], o2 = colw[i2], o3 = colw[i3];
            float w0 = ew[hd * EST + i0], w1 = ew[hd * EST + i1];
            float w2 = ew[hd * EST + i2], w3 = ew[hd * EST + i3];
            uint4 u0 = *reinterpret_cast<const uint4*>(hbase + o0 + cg8);
            uint4 u1 = *reinterpret_cast<const uint4*>(hbase + o1 + cg8);
            uint4 u2 = *reinterpret_cast<const uint4*>(hbase + o2 + cg8);
            uint4 u3 = *reinterpret_cast<const uint4*>(hbase + o3 + cg8);
            fma_mix_pair(acc[0], acc[1], u0.x, w0);
            fma_mix_pair(acc[2], acc[3], u0.y, w0);
            fma_mix_pair(acc[4], acc[5], u0.z, w0);
            fma_mix_pair(acc[6], acc[7], u0.w, w0);
            fma_mix_pair(acc[0], acc[1], u1.x, w1);
            fma_mix_pair(acc[2], acc[3], u1.y, w1);
            fma_mix_pair(acc[4], acc[5], u1.z, w1);
            fma_mix_pair(acc[6], acc[7], u1.w, w1);
            fma_mix_pair(acc[0], acc[1], u2.x, w2);
            fma_mix_pair(acc[2], acc[3], u2.y, w2);
            fma_mix_pair(acc[4], acc[5], u2.z, w2);
            fma_mix_pair(acc[6], acc[7], u2.w, w2);
            fma_mix_pair(acc[0], acc[1], u3.x, w3);
            fma_mix_pair(acc[2], acc[3], u3.y, w3);
            fma_mix_pair(acc[4], acc[5], u3.z, w3);
            fma_mix_pair(acc[6], acc[7], u3.w, w3);
        }
    }

    // denominator: reduce over edge groups (strides 4..32 keep head fixed)
#pragma unroll
    for (int off = 4; off < 64; off <<= 1) pdp += __shfl_xor(pdp, off);
    if (lane < 4) den_lds[wave][ha] = pdp;

    // reduce acc across edge slots
#pragma unroll
    for (int j = 0; j < 8; ++j) acc[j] += __shfl_xor(acc[j], 32);

    if (es == 0) {
        float inv = 1.0f / den_lds[wave][hd];
        float4 b0 = *reinterpret_cast<const float4*>(&bias[cg8]);
        float4 b1 = *reinterpret_cast<const float4*>(&bias[cg8 + 4]);
        float bv[8] = {b0.x, b0.y, b0.z, b0.w, b1.x, b1.y, b1.z, b1.w};
        ushort_t o[8];
#pragma unroll
        for (int j = 0; j < 8; ++j) {
            float r = acc[j] * inv + bv[j];
            if (do_elu && r < 0.f) r = expm1f(r);
            o[j] = f2h_bits(r);
        }
        *reinterpret_cast<uint4*>(&outh[((size_t)b * NN + n) * HC + cg8]) =
            *reinterpret_cast<uint4*>(&o[0]);
    }
}

// ---------------- launch ----------------

extern "C" void kernel_launch(void* const* d_in, const int* in_sizes, int n_in,
                              void* d_out, int out_size, void* d_ws, size_t ws_size,
                              hipStream_t stream) {
    const float* x      = (const float*)d_in[0];   // [2, NN, FIN]
    const int*   ei     = (const int*)d_in[1];     // [2, NE]
    const float* W1     = (const float*)d_in[2];   // [FIN, HC]
    const float* a_src1 = (const float*)d_in[3];
    const float* a_dst1 = (const float*)d_in[4];
    const float* b1     = (const float*)d_in[5];
    const float* W2     = (const float*)d_in[6];   // [HC, HC]
    const float* a_src2 = (const float*)d_in[7];
    const float* a_dst2 = (const float*)d_in[8];
    const float* b2     = (const float*)d_in[9];
    const float* Wf     = (const float*)d_in[10];  // [HC, CH]
    const float* bf     = (const float*)d_in[11];
    float* out = (float*)d_out;                    // [2, NN, CH]

    const int M2 = 2 * NN;
    float* ws = (float*)d_ws;
    float* Ssrc = ws;                              // M2*NH
    float* Sdst = Ssrc + (size_t)M2 * NH;          // M2*NH
    ushort_t* Hb16 = (ushort_t*)(Sdst + (size_t)M2 * NH);  // M2*HC f16 (gemm out)
    ushort_t* Ob16 = Hb16 + (size_t)M2 * HC;       // M2*HC f16 (agg out)
    ushort_t* Wt1  = Ob16 + (size_t)M2 * HC;       // HC*FIN
    ushort_t* Wt2  = Wt1 + (size_t)HC * FIN;       // HC*HC
    ushort_t* Wtf  = Wt2 + (size_t)HC * HC;        // CH*HC
    int* counts = (int*)(Wtf + (size_t)CH * HC);
    int* rowptr = counts + NN;                     // NN+1
    int* cursor = rowptr + (NN + 1);
    int* colidx = cursor + NN;                     // ETOT
    int* bsum   = colidx + ETOT;                   // SCB
    int* bpre   = bsum + SCB;                      // SCB

    // ---- CSR hist (fused with weight transposes) + parallel scan ----
    hipMemsetAsync(counts, 0, (size_t)NN * sizeof(int), stream);
    k_hist_setup<<<HB + SB, 256, 0, stream>>>(ei, counts, W1, W2, Wf, Wt1, Wt2, Wtf);
    k_scan_part<<<SCB, 256, 0, stream>>>(counts, bsum);
    k_scan_top<<<1, 128, 0, stream>>>(bsum, bpre);
    k_scan_apply<<<SCB, 256, 0, stream>>>(counts, bpre, rowptr, cursor);

    const int gAgg = M2 / 4;                   // 10000 blocks x 4 waves
    // scatter || layer-1 GEMM (f32 x, scores fused into epilogue)
    k_scatter_gemm1<<<HB + GM128 * (HC / 128), 256, 0, stream>>>(
        ei, cursor, colidx, x, Wt1, Hb16, a_src1, a_dst1, Ssrc, Sdst, M2);
    k_agg<<<gAgg, 256, 0, stream>>>(Hb16, Ssrc, Sdst, rowptr, colidx, b1, Ob16, 1);
    // layer 2
    k_gemm128<<<dim3(GM128, HC / 128), 256, 0, stream>>>(Ob16, Wt2, Hb16, a_src2, a_dst2,
                                                         Ssrc, Sdst, M2, HC, HC);
    k_agg<<<gAgg, 256, 0, stream>>>(Hb16, Ssrc, Sdst, rowptr, colidx, b2, Ob16, 0);
    // final projection (64-wide): f32 out + bias
    k_gemm_mfma<<<dim3((M2 + 63) / 64, CH / 64), 256, 0, stream>>>(Ob16, Wtf, out, bf, M2, HC, CH);
}